// Round 8
// baseline (385.307 us; speedup 1.0000x reference)
//
#include <hip/hip_runtime.h>
#include <hip/hip_bf16.h>
#include <cstddef>

// RSAGEConv: 2-layer hetero SAGE (mean agg), N=50000, R=3, E=600000, 128->256->128.
// fp32 in/out. CSR gather aggregation + bf16 MFMA GEMMs.
//
// r18 = r17 (348.7us) with gemm1m+gemm2m FUSED into gemm12 (1-D grid, one block
// per 128-row stripe):
//   phase 1: h_tile[128x256] = relu(Abig_stripe @ B1t^T + bias1), K=512,
//            acc[2][4][4], As staged (global_load_lds), B1t frags direct from
//            L2 (256KB hot). h -> LDS hT[128][264] (pad: row stride 528B ->
//            8 accesses/bank = conflict-free floor for ds_read_b128).
//   phase 2: 4 col-tiles, K=256 from LDS, B2t direct -> out(+bias2) | y.
//   h buffer DELETED (was 25.6MB write + 102MB raw 4x re-read); Abig re-read
//   2x -> 1x. y PACKED INTO ABIG's own stripe: 1-D grid makes block s the
//   exclusive reader of Abig rows [128s,128s+128) (131KB); its y (3x128x256B
//   = 96KB) overwrites that region after phase 1 -> no hazard, no new ws.
//   ypack addr: uint ofs = (s>>7)<<15 | rel<<13 | (s&127)<<6 (rows 256B contig).
//
// gather2 pinned at 70us / FETCH 221MB / 3.2 TB/s = random-row HBM floor (r16/r17:
// VALU trims moved VALUBusy not dur). gather1 same structure, same floor.
//
// DEAD ENDS (do not revisit):
//  - LDS fp32 atomic accumulation gathers: r13 1300us, r15 1546us.
//  - Global fp32 atomicAdd hot path: CAS loop, 150MB write. (r13)
//  - Per-node/per-bucket global cursor atomics: same-addr serialization. (r6/r11)
//  - Single-block scan over 64K ints: 50us hidden serial chain. (r12)
//  - VALU trims on memory-floor gathers: no effect. (r16)

#define NN 50000
#define RR 3
#define EE 600000
#define DIN 128
#define DHID 256
#define DOUT 128
#define NRN (RR * NN)

#define RANGE 256                    // nodes per bin
#define NRANGE ((NN + RANGE - 1) / RANGE)   // 196
#define NBIN (RR * NRANGE)           // 588
#define EPB 4096                     // edges per multisplit block
#define NBLK ((RR * EE + EPB - 1) / EPB)    // 440
#define MAXB2 4096                   // max records per bin (mean 3072, +18 sigma)
#define MTOT (NBIN * NBLK)           // 258720

typedef __hip_bfloat16 bf16;
typedef __hip_bfloat162 bf162;
typedef unsigned short u16;
typedef __attribute__((ext_vector_type(8))) short short8;
typedef __attribute__((ext_vector_type(4))) float floatx4;

__device__ __forceinline__ void async_copy16(const void* g, void* l) {
    __builtin_amdgcn_global_load_lds((const __attribute__((address_space(1))) void*)g,
                                     (__attribute__((address_space(3))) void*)l, 16, 0, 0);
}

// ---------------- fused binhist + prep ----------------
#define PREP_A (NN * 64)
#define PREP_B (256 * 512)
#define PREP_C (512 * 256)
#define PREP_D 384
#define PREP_TOTAL (PREP_A + PREP_B + PREP_C + PREP_D)
#define PREP_BLOCKS ((PREP_TOTAL + 255) / 256)

__global__ __launch_bounds__(256) void hist_prep(const int* __restrict__ dst,
        int* __restrict__ m,
        const float* __restrict__ x,
        const float* __restrict__ Ws1, const float* __restrict__ Wn1,
        const float* __restrict__ b1,
        const float* __restrict__ Ws2, const float* __restrict__ Wn2,
        const float* __restrict__ b2,
        bf16* __restrict__ Abig, bf16* __restrict__ B1t, bf16* __restrict__ B2t,
        float* __restrict__ bias1, float* __restrict__ bias2) {
    __shared__ int lh[NBIN];
    if (blockIdx.x < NBLK) {
        for (int i = threadIdx.x; i < NBIN; i += 256) lh[i] = 0;
        __syncthreads();
        int base = blockIdx.x * EPB;
        int lim = min(EPB, RR * EE - base);
        for (int i = threadIdx.x; i < lim; i += 256) {
            int e = base + i;
            int r = e / EE;
            int d = dst[e];
            atomicAdd(&lh[r * NRANGE + (d >> 8)], 1);
        }
        __syncthreads();
        for (int i = threadIdx.x; i < NBIN; i += 256) m[i * NBLK + blockIdx.x] = lh[i];
        return;
    }
    int idx = (blockIdx.x - NBLK) * 256 + threadIdx.x;
    if (idx < PREP_A) {
        int n = idx >> 6, c2 = idx & 63;
        float2 v = *(const float2*)&x[(size_t)n * DIN + c2 * 2];
        bf162 o; o.x = __float2bfloat16(v.x); o.y = __float2bfloat16(v.y);
        *(bf162*)&Abig[(size_t)n * 512 + c2 * 2] = o;
        return;
    }
    idx -= PREP_A;
    if (idx < PREP_B) {
        int n = idx >> 9, k = idx & 511;
        float v;
        if (k < 128) {
            v = Ws1[(size_t)k * 256 + n]
              + Ws1[(size_t)(128 + k) * 256 + n]
              + Ws1[(size_t)(256 + k) * 256 + n];
        } else {
            int q = k - 128; int r = q >> 7; int kk = q & 127;
            v = Wn1[((size_t)r * 128 + kk) * 256 + n];
        }
        B1t[(size_t)n * 512 + k] = __float2bfloat16(v);
        return;
    }
    idx -= PREP_B;
    if (idx < PREP_C) {
        int n = idx >> 8, k = idx & 255;
        float v;
        if (n < 128) {
            v = Ws2[(size_t)k * 128 + n]
              + Ws2[(size_t)(256 + k) * 128 + n]
              + Ws2[(size_t)(512 + k) * 128 + n];
        } else {
            int q = n - 128; int r = q >> 7; int nn = q & 127;
            v = Wn2[((size_t)r * 256 + k) * 128 + nn];
        }
        B2t[(size_t)n * 256 + k] = __float2bfloat16(v);
        return;
    }
    idx -= PREP_C;
    if (idx < PREP_D) {
        if (idx < 256) {
            bias1[idx] = b1[idx] + b1[256 + idx] + b1[512 + idx];
        } else {
            int j = idx - 256;
            bias2[j] = b2[j] + b2[128 + j] + b2[256 + j];
        }
    }
}

// ---------------- multisplit pass 2: multi-block scan of [NBIN][NBLK] ----------------
__global__ __launch_bounds__(256) void mscan_blocks(int* __restrict__ data,
        int* __restrict__ bsums, int n) {
    int t = threadIdx.x;
    int base = blockIdx.x * 1024 + t * 4;
    int v[4];
    #pragma unroll
    for (int i = 0; i < 4; ++i) v[i] = (base + i < n) ? data[base + i] : 0;
    int s = v[0] + v[1] + v[2] + v[3];
    int lane = t & 63, wid = t >> 6;
    int sc = s;
    #pragma unroll
    for (int d = 1; d < 64; d <<= 1) {
        int tt = __shfl_up(sc, d, 64);
        if (lane >= d) sc += tt;
    }
    __shared__ int wsum[4], woff[4];
    if (lane == 63) wsum[wid] = sc;
    __syncthreads();
    if (t == 0) {
        int a = 0;
        #pragma unroll
        for (int i = 0; i < 4; ++i) { woff[i] = a; a += wsum[i]; }
    }
    __syncthreads();
    int run = sc - s + woff[wid];
    #pragma unroll
    for (int i = 0; i < 4; ++i) {
        if (base + i < n) data[base + i] = run;
        run += v[i];
    }
    if (t == 255) bsums[blockIdx.x] = woff[3] + wsum[3];
}

__global__ __launch_bounds__(256) void mscan_sums(int* __restrict__ bsums, int nb) {
    int t = threadIdx.x;
    int v = (t < nb) ? bsums[t] : 0;
    int lane = t & 63, wid = t >> 6;
    int sc = v;
    #pragma unroll
    for (int d = 1; d < 64; d <<= 1) {
        int tt = __shfl_up(sc, d, 64);
        if (lane >= d) sc += tt;
    }
    __shared__ int wsum[4], woff[4];
    if (lane == 63) wsum[wid] = sc;
    __syncthreads();
    if (t == 0) {
        int a = 0;
        #pragma unroll
        for (int i = 0; i < 4; ++i) { woff[i] = a; a += wsum[i]; }
    }
    __syncthreads();
    if (t < nb) bsums[t] = sc - v + woff[wid];
}

__global__ __launch_bounds__(256) void mscan_fixup(int* __restrict__ m,
        const int* __restrict__ bsums, int* __restrict__ binbase) {
    int i = blockIdx.x * 256 + threadIdx.x;
    if (i < MTOT) {
        int v = m[i] + bsums[i >> 10];
        m[i] = v;
        int q = i / NBLK;
        if (i - q * NBLK == 0) binbase[q] = v;
    }
    if (i == 0) binbase[NBIN] = RR * EE;
}

// ---------------- multisplit pass 3: rank via LDS cursors, block-private segments ----------------
__global__ __launch_bounds__(256) void binscatter(const int* __restrict__ src,
        const int* __restrict__ dst, const int* __restrict__ m,
        unsigned* __restrict__ ebuf) {
    __shared__ int scur[NBIN];
    for (int i = threadIdx.x; i < NBIN; i += 256) scur[i] = m[i * NBLK + blockIdx.x];
    __syncthreads();
    int base = blockIdx.x * EPB;
    int lim = min(EPB, RR * EE - base);
    for (int i = threadIdx.x; i < lim; i += 256) {
        int e = base + i;
        int r = e / EE;
        int d = dst[e];
        int pos = atomicAdd(&scur[r * NRANGE + (d >> 8)], 1);
        ebuf[pos] = ((unsigned)(d & 255) << 16) | (unsigned)src[e];
    }
}

// ---------------- per-bin LDS counting sort -> rowptr + coalesced u16 col ----------------
__global__ __launch_bounds__(256) void binsort(const int* __restrict__ binbase,
        const unsigned* __restrict__ ebuf, u16* __restrict__ col,
        int* __restrict__ rowptr) {
    int b = blockIdx.x;
    int r = b / NRANGE, rb = b - r * NRANGE;
    int node0 = rb * RANGE;
    int nn = min(RANGE, NN - node0);
    int beg = binbase[b], end = binbase[b + 1];
    int cnt = min(end - beg, MAXB2);

    __shared__ unsigned eb[MAXB2];
    __shared__ u16 sb[MAXB2];
    __shared__ int lh[RANGE], lc[RANGE];
    __shared__ int wsum[4], woff[4];

    for (int i = threadIdx.x; i < cnt; i += 256) eb[i] = ebuf[beg + i];
    lh[threadIdx.x] = 0;
    __syncthreads();
    for (int i = threadIdx.x; i < cnt; i += 256) atomicAdd(&lh[eb[i] >> 16], 1);
    __syncthreads();
    {   // exclusive scan of 256 counters (4 waves)
        int t = threadIdx.x, lane = t & 63, wid = t >> 6;
        int v = lh[t];
        int sc = v;
        #pragma unroll
        for (int d = 1; d < 64; d <<= 1) {
            int tt = __shfl_up(sc, d, 64);
            if (lane >= d) sc += tt;
        }
        if (lane == 63) wsum[wid] = sc;
        __syncthreads();
        if (t == 0) {
            int a = 0;
            #pragma unroll
            for (int i = 0; i < 4; ++i) { woff[i] = a; a += wsum[i]; }
        }
        __syncthreads();
        int excl = sc - v + woff[wid];
        lc[t] = excl;
        if (t < nn) rowptr[r * NN + node0 + t] = beg + excl;
        if (t == 0) rowptr[r * NN + node0 + nn] = end;
    }
    __syncthreads();
    for (int i = threadIdx.x; i < cnt; i += 256) {
        unsigned e = eb[i];
        int pos = atomicAdd(&lc[e >> 16], 1);
        sb[pos] = (u16)(e & 0xffffu);
    }
    __syncthreads();
    for (int i = threadIdx.x; i < cnt; i += 256) col[beg + i] = sb[i];
}

__device__ __forceinline__ float bflo(unsigned u) { return __uint_as_float(u << 16); }
__device__ __forceinline__ float bfhi(unsigned u) { return __uint_as_float(u & 0xffff0000u); }

// ---------------- gather1: Abig[n][128+128r..] = mean_{s in col[r,n]} bf16x[s] ----------------
__global__ __launch_bounds__(256) void gather1(const int* __restrict__ rowptr,
        const u16* __restrict__ col, bf16* __restrict__ Abig) {
    int g = blockIdx.x * 4 + (threadIdx.x >> 6);   // r*NN + n
    int lane = threadIdx.x & 63;
    int r = g / NN;
    int n = g - r * NN;
    int beg = rowptr[g], end = rowptr[g + 1];
    const unsigned* xb = (const unsigned*)Abig;    // row stride 256 uints
    float acc0 = 0.f, acc1 = 0.f;
    for (int base = beg; base < end; base += 64) {
        int cnt = min(64, end - base);
        int cidx = (lane < cnt) ? (int)col[base + lane] : 0;
        int j = 0;
        for (; j + 8 <= cnt; j += 8) {
            const unsigned* p0 = xb + (size_t)__builtin_amdgcn_readlane(cidx, j)     * 256;
            const unsigned* p1 = xb + (size_t)__builtin_amdgcn_readlane(cidx, j + 1) * 256;
            const unsigned* p2 = xb + (size_t)__builtin_amdgcn_readlane(cidx, j + 2) * 256;
            const unsigned* p3 = xb + (size_t)__builtin_amdgcn_readlane(cidx, j + 3) * 256;
            const unsigned* p4 = xb + (size_t)__builtin_amdgcn_readlane(cidx, j + 4) * 256;
            const unsigned* p5 = xb + (size_t)__builtin_amdgcn_readlane(cidx, j + 5) * 256;
            const unsigned* p6 = xb + (size_t)__builtin_amdgcn_readlane(cidx, j + 6) * 256;
            const unsigned* p7 = xb + (size_t)__builtin_amdgcn_readlane(cidx, j + 7) * 256;
            unsigned u0 = p0[lane], u1 = p1[lane], u2 = p2[lane], u3 = p3[lane];
            unsigned u4 = p4[lane], u5 = p5[lane], u6 = p6[lane], u7 = p7[lane];
            acc0 += bflo(u0) + bflo(u1) + bflo(u2) + bflo(u3)
                  + bflo(u4) + bflo(u5) + bflo(u6) + bflo(u7);
            acc1 += bfhi(u0) + bfhi(u1) + bfhi(u2) + bfhi(u3)
                  + bfhi(u4) + bfhi(u5) + bfhi(u6) + bfhi(u7);
        }
        for (; j + 4 <= cnt; j += 4) {
            const unsigned* p0 = xb + (size_t)__builtin_amdgcn_readlane(cidx, j)     * 256;
            const unsigned* p1 = xb + (size_t)__builtin_amdgcn_readlane(cidx, j + 1) * 256;
            const unsigned* p2 = xb + (size_t)__builtin_amdgcn_readlane(cidx, j + 2) * 256;
            const unsigned* p3 = xb + (size_t)__builtin_amdgcn_readlane(cidx, j + 3) * 256;
            unsigned u0 = p0[lane], u1 = p1[lane], u2 = p2[lane], u3 = p3[lane];
            acc0 += bflo(u0) + bflo(u1) + bflo(u2) + bflo(u3);
            acc1 += bfhi(u0) + bfhi(u1) + bfhi(u2) + bfhi(u3);
        }
        for (; j < cnt; ++j) {
            const unsigned* p = xb + (size_t)__builtin_amdgcn_readlane(cidx, j) * 256;
            unsigned u = p[lane];
            acc0 += bflo(u);
            acc1 += bfhi(u);
        }
    }
    float inv = 1.0f / fmaxf((float)(end - beg), 1.0f);
    bf162 o;
    o.x = __float2bfloat16(acc0 * inv);
    o.y = __float2bfloat16(acc1 * inv);
    *(bf162*)&Abig[(size_t)n * 512 + 128 + r * 128 + lane * 2] = o;
}

// ---------------- FUSED GEMM: Abig[N][512] -> h(LDS) -> out fp32 + ypack(bf16, in Abig) ----
// Block s owns rows [128s, 128s+128). Phase 1: h=relu(A@B1t^T+b1) K=512 -> LDS.
// Phase 2: 4 col-tiles K=256: ct=0 -> out+b2; ct=1..3 -> ypack rel=ct-1 written
// into THIS STRIPE's Abig bytes (exclusively owned, already consumed).
__global__ __launch_bounds__(256) void gemm12(bf16* AY,
        const bf16* __restrict__ B1t, const bf16* __restrict__ B2t,
        const float* __restrict__ bias1, const float* __restrict__ bias2,
        float* __restrict__ out) {
    __shared__ bf16 hT[128 * 264];      // pad 264: row stride 528B -> conflict-free b128
    __shared__ short As[128 * 32];
    const int t = threadIdx.x;
    const int wv = t >> 6, lane = t & 63;
    const int wr = wv >> 1, wc = wv & 1;
    const int m16 = lane & 15, kg = lane >> 4;
    const int s = blockIdx.x;
    const int row0 = s * 128;
    const int ldrow = t >> 2, ldk = (t & 3) * 8;
    const int arow0 = min(row0 + ldrow, NN - 1);
    const int arow1 = min(row0 + ldrow + 64, NN - 1);
    const short* Ag0 = (const short*)AY + (size_t)arow0 * 512 + ldk;
    const short* Ag1 = (const short*)AY + (size_t)arow1 * 512 + ldk;
    short* AsW = &As[(size_t)wv * 512];
    const short* B1s = (const short*)B1t;
    const short* B2s = (const short*)B2t;

    // ---- phase 1: h[128x256] = relu(A@B1t^T + bias1), K=512 ----
    floatx4 acc1[2][4][4] = {};
    for (int kb = 0; kb < 512; kb += 32) {
        async_copy16(Ag0 + kb, AsW);
        async_copy16(Ag1 + kb, AsW + 2048);
        __syncthreads();
        short8 a[4];
        #pragma unroll
        for (int i = 0; i < 4; ++i)
            a[i] = *(const short8*)&As[(wr * 64 + i * 16 + m16) * 32 + kg * 8];
        #pragma unroll
        for (int ch = 0; ch < 2; ++ch) {
            short8 b[4];
            #pragma unroll
            for (int j = 0; j < 4; ++j)
                b[j] = *(const short8*)&B1s[(size_t)(ch * 128 + wc * 64 + j * 16 + m16) * 512 + kb + kg * 8];
            #pragma unroll
            for (int i = 0; i < 4; ++i)
                #pragma unroll
                for (int j = 0; j < 4; ++j)
                    acc1[ch][i][j] = __builtin_amdgcn_mfma_f32_16x16x32_bf16(a[i], b[j], acc1[ch][i][j], 0, 0, 0);
        }
        __syncthreads();
    }
    #pragma unroll
    for (int ch = 0; ch < 2; ++ch)
        #pragma unroll
        for (int j = 0; j < 4; ++j) {
            int c = ch * 128 + wc * 64 + j * 16 + m16;
            float bj = bias1[c];
            #pragma unroll
            for (int i = 0; i < 4; ++i) {
                int rl = wr * 64 + i * 16 + kg * 4;
                #pragma unroll
                for (int reg = 0; reg < 4; ++reg)
                    hT[(rl + reg) * 264 + c] =
                        __float2bfloat16(fmaxf(acc1[ch][i][j][reg] + bj, 0.f));
            }
        }
    __syncthreads();

    // ---- phase 2: 4 col-tiles of [128x128], K=256 from LDS ----
    #pragma unroll 1
    for (int ct = 0; ct < 4; ++ct) {
        floatx4 acc[4][4] = {};
        for (int kb = 0; kb < 256; kb += 32) {
            short8 a[4], b[4];
            #pragma unroll
            for (int i = 0; i < 4; ++i)
                a[i] = *(const short8*)&((const short*)hT)[(wr * 64 + i * 16 + m16) * 264 + kb + kg * 8];
            #pragma unroll
            for (int j = 0; j < 4; ++j)
                b[j] = *(const short8*)&B2s[(size_t)(ct * 128 + wc * 64 + j * 16 + m16) * 256 + kb + kg * 8];
            #pragma unroll
            for (int i = 0; i < 4; ++i)
                #pragma unroll
                for (int j = 0; j < 4; ++j)
                    acc[i][j] = __builtin_amdgcn_mfma_f32_16x16x32_bf16(a[i], b[j], acc[i][j], 0, 0, 0);
        }
        if (ct == 0) {
            #pragma unroll
            for (int j = 0; j < 4; ++j) {
                int c = wc * 64 + j * 16 + m16;
                float bj = bias2[c];
                #pragma unroll
                for (int i = 0; i < 4; ++i) {
                    int rl = wr * 64 + i * 16 + kg * 4;
                    #pragma unroll
                    for (int reg = 0; reg < 4; ++reg) {
                        int r = row0 + rl + reg;
                        if (r < NN) out[(size_t)r * DOUT + c] = acc[i][j][reg] + bj;
                    }
                }
            }
        } else {
            int rel = ct - 1;
            bf16* yp = AY + ((size_t)s << 16) + ((size_t)rel << 14);
            #pragma unroll
            for (int j = 0; j < 4; ++j) {
                int c = wc * 64 + j * 16 + m16;
                #pragma unroll
                for (int i = 0; i < 4; ++i) {
                    int rl = wr * 64 + i * 16 + kg * 4;
                    #pragma unroll
                    for (int reg = 0; reg < 4; ++reg) {
                        if (row0 + rl + reg < NN)
                            yp[((rl + reg) << 7) + c] = __float2bfloat16(acc[i][j][reg]);
                    }
                }
            }
        }
        __syncthreads();   // hT reads of this tile done before next tile / exit
    }
}

// ---------------- gather2: out[n] += sum_r mean_{s in col[r,n]} ypack[r][s] ----------------
// ypack row (rel r, src sidx): uints at (sidx>>7)<<15 | r<<13 | (sidx&127)<<6.
__global__ __launch_bounds__(256) void gather2(const bf16* __restrict__ ypack,
        const int* __restrict__ rowptr, const u16* __restrict__ col,
        float* __restrict__ out) {
    int n = blockIdx.x * 4 + (threadIdx.x >> 6);
    int lane = threadIdx.x & 63;
    float2 acc = *(float2*)&out[(size_t)n * DOUT + lane * 2];
    const unsigned* yb = (const unsigned*)ypack;
    #pragma unroll
    for (int r = 0; r < RR; ++r) {
        int g = r * NN + n;
        int beg = rowptr[g], end = rowptr[g + 1];
        float a0 = 0.f, a1 = 0.f;
        const size_t rbase = (size_t)r << 13;
        for (int base = beg; base < end; base += 64) {
            int cnt = min(64, end - base);
            int cidx = (lane < cnt) ? (int)col[base + lane] : 0;
            int j = 0;
            for (; j + 8 <= cnt; j += 8) {
                int s0 = __builtin_amdgcn_readlane(cidx, j);
                int s1 = __builtin_amdgcn_readlane(cidx, j + 1);
                int s2 = __builtin_amdgcn_readlane(cidx, j + 2);
                int s3 = __builtin_amdgcn_readlane(cidx, j + 3);
                int s4 = __builtin_amdgcn_readlane(cidx, j + 4);
                int s5 = __builtin_amdgcn_readlane(cidx, j + 5);
                int s6 = __builtin_amdgcn_readlane(cidx, j + 6);
                int s7 = __builtin_amdgcn_readlane(cidx, j + 7);
                const unsigned* p0 = yb + rbase + ((size_t)(s0 >> 7) << 15) + ((s0 & 127) << 6);
                const unsigned* p1 = yb + rbase + ((size_t)(s1 >> 7) << 15) + ((s1 & 127) << 6);
                const unsigned* p2 = yb + rbase + ((size_t)(s2 >> 7) << 15) + ((s2 & 127) << 6);
                const unsigned* p3 = yb + rbase + ((size_t)(s3 >> 7) << 15) + ((s3 & 127) << 6);
                const unsigned* p4 = yb + rbase + ((size_t)(s4 >> 7) << 15) + ((s4 & 127) << 6);
                const unsigned* p5 = yb + rbase + ((size_t)(s5 >> 7) << 15) + ((s5 & 127) << 6);
                const unsigned* p6 = yb + rbase + ((size_t)(s6 >> 7) << 15) + ((s6 & 127) << 6);
                const unsigned* p7 = yb + rbase + ((size_t)(s7 >> 7) << 15) + ((s7 & 127) << 6);
                unsigned u0 = p0[lane], u1 = p1[lane], u2 = p2[lane], u3 = p3[lane];
                unsigned u4 = p4[lane], u5 = p5[lane], u6 = p6[lane], u7 = p7[lane];
                a0 += bflo(u0) + bflo(u1) + bflo(u2) + bflo(u3)
                    + bflo(u4) + bflo(u5) + bflo(u6) + bflo(u7);
                a1 += bfhi(u0) + bfhi(u1) + bfhi(u2) + bfhi(u3)
                    + bfhi(u4) + bfhi(u5) + bfhi(u6) + bfhi(u7);
            }
            for (; j < cnt; ++j) {
                int sj = __builtin_amdgcn_readlane(cidx, j);
                const unsigned* p = yb + rbase + ((size_t)(sj >> 7) << 15) + ((sj & 127) << 6);
                unsigned u = p[lane];
                a0 += bflo(u);
                a1 += bfhi(u);
            }
        }
        float inv = 1.0f / fmaxf((float)(end - beg), 1.0f);
        acc.x += a0 * inv;
        acc.y += a1 * inv;
    }
    *(float2*)&out[(size_t)n * DOUT + lane * 2] = acc;
}

// ---------------- launch ----------------
extern "C" void kernel_launch(void* const* d_in, const int* in_sizes, int n_in,
                              void* d_out, int out_size, void* d_ws, size_t ws_size,
                              hipStream_t stream) {
    const float* x       = (const float*)d_in[0];
    const int*   src     = (const int*)  d_in[1];
    const int*   dst     = (const int*)  d_in[2];
    const float* Wself1  = (const float*)d_in[3];
    const float* Wneigh1 = (const float*)d_in[4];
    const float* b1      = (const float*)d_in[5];
    const float* Wself2  = (const float*)d_in[6];
    const float* Wneigh2 = (const float*)d_in[7];
    const float* b2      = (const float*)d_in[8];
    float* out = (float*)d_out;

    char* ws = (char*)d_ws;
    int*      mtx     = (int*)     (ws + 0x0000000ull);   // [588][440] ints (1.03MB)
    int*      binbase = (int*)     (ws + 0x0110000ull);   // [589]
    int*      bsums   = (int*)     (ws + 0x0120000ull);   // [253]
    int*      rowptr  = (int*)     (ws + 0x0140000ull);   // [NRN+1] (600KB)
    float*    bias1   = (float*)   (ws + 0x01E1000ull);
    float*    bias2   = (float*)   (ws + 0x01E2000ull);
    unsigned* ebuf    = (unsigned*)(ws + 0x0200000ull);   // [1.8M] packed (d&255)<<16|src
    bf16*     B1t     = (bf16*)    (ws + 0x0A00000ull);
    bf16*     B2t     = (bf16*)    (ws + 0x0A40000ull);
    bf16*     Abig    = (bf16*)    (ws + 0x0B00000ull);   // [N][512] bf16 (51.2MB); ypack overlays per-stripe
    u16*      col     = (u16*)     (ws + 0x5600000ull);   // [1.8M] u16 (3.6MB)

    hist_prep<<<NBLK + PREP_BLOCKS, 256, 0, stream>>>(
        dst, mtx, x, Wself1, Wneigh1, b1, Wself2, Wneigh2, b2,
        Abig, B1t, B2t, bias1, bias2);

    mscan_blocks<<<(MTOT + 1023) / 1024, 256, 0, stream>>>(mtx, bsums, MTOT);
    mscan_sums<<<1, 256, 0, stream>>>(bsums, (MTOT + 1023) / 1024);
    mscan_fixup<<<(MTOT + 255) / 256, 256, 0, stream>>>(mtx, bsums, binbase);
    binscatter<<<NBLK, 256, 0, stream>>>(src, dst, mtx, ebuf);
    binsort<<<NBIN, 256, 0, stream>>>(binbase, ebuf, col, rowptr);

    gather1<<<NRN / 4, 256, 0, stream>>>(rowptr, col, Abig);

    gemm12<<<(NN + 127) / 128, 256, 0, stream>>>(Abig, B1t, B2t, bias1, bias2, out);

    gather2<<<NN / 4, 256, 0, stream>>>(Abig, rowptr, col, out);
}